// Round 8
// baseline (17600.331 us; speedup 1.0000x reference)
//
#include <hip/hip_runtime.h>
#include <hip/hip_bf16.h>

#define SEQ  512
#define HID  1024
#define G4   4096
#define NBLK 128   // blocks per layer; grid = 256
#define RD   8     // tagged h-ring depth (slots)
#define SLOT 32768 // u64 per slot: 64 rows x 512 (each u64 = tag<<32 | 2 bf16)

typedef short bf16x8 __attribute__((ext_vector_type(8)));
typedef float f32x4  __attribute__((ext_vector_type(4)));
typedef unsigned long long u64;

static __device__ __forceinline__ unsigned short f2b(float f) {
  union { float f; unsigned u; } v; v.f = f;
  unsigned r = (v.u + 0x7FFFu + ((v.u >> 16) & 1u)) >> 16;  // RNE
  return (unsigned short)r;
}
static __device__ __forceinline__ float b2f_lo(unsigned u) {
  union { unsigned u; float f; } v; v.u = u << 16; return v.f;
}
static __device__ __forceinline__ float b2f_hi(unsigned u) {
  union { unsigned u; float f; } v; v.u = u & 0xFFFF0000u; return v.f;
}
static __device__ __forceinline__ u64 gld(const u64* p) {
  return __hip_atomic_load(p, __ATOMIC_RELAXED, __HIP_MEMORY_SCOPE_AGENT);
}

// x (B,S,I) f32 -> xb row-major (S*B, I) bf16, row r = s*64+b
__global__ __launch_bounds__(256) void k_castx(const float* __restrict__ x,
                                               unsigned short* __restrict__ xb) {
  int idx = blockIdx.x * 256 + threadIdx.x;
  int r = idx >> 8, kq = idx & 255;
  int b = r & 63, s = r >> 6;
  float4 v = *reinterpret_cast<const float4*>(x + ((size_t)b * SEQ + s) * HID + (size_t)kq * 4);
  ushort4 o;
  o.x = f2b(v.x); o.y = f2b(v.y); o.z = f2b(v.z); o.w = f2b(v.w);
  *reinterpret_cast<ushort4*>(xb + (size_t)r * HID + kq * 4) = o;
}

// W (K=1024, N=4096) f32 -> WT (N=4096, K=1024) bf16
__global__ __launch_bounds__(256) void k_wtrans(const float* __restrict__ W,
                                                unsigned short* __restrict__ WT) {
  __shared__ float tls[32][33];
  int tile = blockIdx.x;
  int nt = tile & 127, kt = tile >> 7;
  int tx = threadIdx.x & 31, ty = threadIdx.x >> 5;
  int k0 = kt * 32, n0 = nt * 32;
  for (int i = 0; i < 4; ++i)
    tls[ty + 8 * i][tx] = W[(size_t)(k0 + ty + 8 * i) * G4 + n0 + tx];
  __syncthreads();
  for (int i = 0; i < 4; ++i)
    WT[(size_t)(n0 + ty + 8 * i) * HID + k0 + tx] = f2b(tls[tx][ty + 8 * i]);
}

static __device__ __forceinline__ void seq_wait(unsigned* p, unsigned tgt) {
  long sp = 0;
  while (__hip_atomic_load(p, __ATOMIC_ACQUIRE, __HIP_MEMORY_SCOPE_WORKGROUP) < tgt) {
    if (++sp > 20000000L) break;   // bailout: wrong answer beats a hang
  }
}
static __device__ __forceinline__ void seq_pub(unsigned* p, unsigned v, int lane) {
  asm volatile("s_waitcnt lgkmcnt(0)" ::: "memory");   // LDS writes/reads done
  if (lane == 0)
    __hip_atomic_store(p, v, __ATOMIC_RELAXED, __HIP_MEMORY_SCOPE_WORKGROUP);
}

// Both LSTM layers, one persistent launch. Blocks 0-127 layer0, 128-255 layer1.
// Sync redesign (r8): h is exchanged through depth-8 rings of TAGGED u64
// entries (tag=step+1 | 2 bf16). The publish IS the data store (no drain, no
// flags); readers spin on the data with sc1 loads, group-pipelined so loads
// of group g+1 fly while group g is verified+MFMA'd. No per-step
// __syncthreads: x-wave i <-> h-wave i hand x_lds buffers over via LDS seq
// counters (lgkmcnt-only). Rings cleared by in-launch memset (replay-safe).
__global__ __launch_bounds__(512, 1) void k_scan2(
    const unsigned short* __restrict__ xb,
    const unsigned short* __restrict__ WxT0, const unsigned short* __restrict__ WhT0,
    const float* __restrict__ b0,
    const unsigned short* __restrict__ WxT1, const unsigned short* __restrict__ WhT1,
    const float* __restrict__ b1,
    u64* __restrict__ h1t, u64* __restrict__ h2t,
    unsigned* __restrict__ prog,
    float* __restrict__ out) {
  __shared__ unsigned short wlds[32 * 2048];   // 128 KB weights [c][k], swizzled
  __shared__ float x_lds[2][4][8][64];         // x-partials in raw MFMA layout
  __shared__ unsigned xseq[4], hseq[4];

  const int bk  = blockIdx.x;
  const int layer = bk >> 7;
  const int nb  = bk & 127;
  const int tid = threadIdx.x;
  const int w   = tid >> 6;
  const int l   = tid & 63;
  const int lq  = l >> 4, lr = l & 15;
  const int rt  = w & 3;
  const bool is_h = (w >= 4);

  const unsigned short* WxT = layer ? WxT1 : WxT0;
  const unsigned short* WhT = layer ? WhT1 : WhT0;
  const float* bias = layer ? b1 : b0;
  u64* hring = layer ? h2t : h1t;          // ring this layer WRITES
  float* fout = layer ? out : nullptr;

  if (tid < 4) { xseq[tid] = 0; hseq[tid] = 0; }

  // ---- one-time: stage weight slice into LDS (swizzled byte addr) ----
  {
    int c = tid >> 4, seg = tid & 15;
    int gate = c >> 3, nl = c & 7;
    int gcol = gate * 1024 + nb * 8 + nl;
    const unsigned short* sx = WxT + (size_t)gcol * HID;
    const unsigned short* sh = WhT + (size_t)gcol * HID;
    for (int j = 0; j < 16; ++j) {
      int kk = seg * 128 + j * 8;
      const unsigned short* src = (kk < 1024) ? (sx + kk) : (sh + kk - 1024);
      uint4 v = *reinterpret_cast<const uint4*>(src);
      int db = (c * 4096 + kk * 2) ^ ((c & 7) << 4);
      *reinterpret_cast<uint4*>(reinterpret_cast<char*>(wlds) + db) = v;
    }
  }

  char* wbase = reinterpret_cast<char*>(wlds);
  const int csw = (lr & 7) << 4;
  const int cb0 = (lr) * 4096 + lq * 16;
  const int cb1 = (16 + lr) * 4096 + lq * 16;

  float bias_c[2];
#pragma unroll
  for (int ct = 0; ct < 2; ++ct) {
    int col = ct * 16 + lr;
    bias_c[ct] = bias[(col >> 3) * 1024 + nb * 8 + (col & 7)];
  }

  float cst[4] = {0.f, 0.f, 0.f, 0.f};   // c-state: 4 rows x 1 col per lane

  // tagged matmul-half: A-rows from tagged ring row pointer, K=1024 (8 groups
  // of 4 ks). Loads of group g+1 in flight while group g verifies + MFMAs.
  auto mm_tagged = [&](f32x4 (&acc)[2][4], const u64* rowp, unsigned tag, int koff) {
    u64 qa[16], qb[16];
    auto LDG = [&](u64* d, int g) {
#pragma unroll
      for (int j = 0; j < 4; ++j)
#pragma unroll
        for (int k2 = 0; k2 < 4; ++k2)
          d[j * 4 + k2] = gld(rowp + (size_t)(g * 4 + j) * 16 + k2);
    };
    auto VFY = [&](u64* d, int g) {
      long sp = 0;
      for (;;) {
        bool ok = true;
#pragma unroll
        for (int m = 0; m < 16; ++m) ok &= ((unsigned)(d[m] >> 32) == tag);
        if (ok) break;
        if (++sp > 60000L) break;   // bailout
        LDG(d, g);
      }
    };
    auto MM4 = [&](u64* d, int g) {
#pragma unroll
      for (int j = 0; j < 4; ++j) {
        int ks = g * 4 + j;
        union { unsigned dw[4]; bf16x8 v; } u;
        u.dw[0] = (unsigned)d[j * 4 + 0]; u.dw[1] = (unsigned)d[j * 4 + 1];
        u.dw[2] = (unsigned)d[j * 4 + 2]; u.dw[3] = (unsigned)d[j * 4 + 3];
        bf16x8 bb0 = *reinterpret_cast<const bf16x8*>(wbase + ((cb0 + koff + ks * 64) ^ csw));
        bf16x8 bb1 = *reinterpret_cast<const bf16x8*>(wbase + ((cb1 + koff + ks * 64) ^ csw));
        acc[0][ks & 3] = __builtin_amdgcn_mfma_f32_16x16x32_bf16(u.v, bb0, acc[0][ks & 3], 0, 0, 0);
        acc[1][ks & 3] = __builtin_amdgcn_mfma_f32_16x16x32_bf16(u.v, bb1, acc[1][ks & 3], 0, 0, 0);
      }
    };
    LDG(qa, 0);
    LDG(qb, 1); VFY(qa, 0); MM4(qa, 0);
    LDG(qa, 2); VFY(qb, 1); MM4(qb, 1);
    LDG(qb, 3); VFY(qa, 2); MM4(qa, 2);
    LDG(qa, 4); VFY(qb, 3); MM4(qb, 3);
    LDG(qb, 5); VFY(qa, 4); MM4(qa, 4);
    LDG(qa, 6); VFY(qb, 5); MM4(qb, 5);
    LDG(qb, 7); VFY(qa, 6); MM4(qa, 6);
                VFY(qb, 7); MM4(qb, 7);
  };

  auto mm_plain = [&](f32x4 (&acc)[2][4], const bf16x8* ap) {
#pragma unroll 8
    for (int ks = 0; ks < 32; ++ks) {
      bf16x8 a  = ap[ks * 4];
      bf16x8 bb0 = *reinterpret_cast<const bf16x8*>(wbase + ((cb0 + ks * 64) ^ csw));
      bf16x8 bb1 = *reinterpret_cast<const bf16x8*>(wbase + ((cb1 + ks * 64) ^ csw));
      acc[0][ks & 3] = __builtin_amdgcn_mfma_f32_16x16x32_bf16(a, bb0, acc[0][ks & 3], 0, 0, 0);
      acc[1][ks & 3] = __builtin_amdgcn_mfma_f32_16x16x32_bf16(a, bb1, acc[1][ks & 3], 0, 0, 0);
    }
  };

  auto store_x = [&](f32x4 (&acc)[2][4], int bufn) {
#pragma unroll
    for (int ct = 0; ct < 2; ++ct) {
      f32x4 s = (acc[ct][0] + acc[ct][1]) + (acc[ct][2] + acc[ct][3]);
      float bc = bias_c[ct];
      x_lds[bufn][w][ct * 4 + 0][l] = s.x + bc;
      x_lds[bufn][w][ct * 4 + 1][l] = s.y + bc;
      x_lds[bufn][w][ct * 4 + 2][l] = s.z + bc;
      x_lds[bufn][w][ct * 4 + 3][l] = s.w + bc;
    }
  };

  __syncthreads();
  if (is_h) __builtin_amdgcn_s_setprio(1);

  if (!is_h) {
    // ================= x-waves =================
    // prologue: projection for step 0 into buf0
    {
      f32x4 acc[2][4] = {};
      if (layer) {
        const u64* rowp = h1t + 0 * SLOT + (size_t)(rt * 16 + lr) * 512 + lq * 4;
        mm_tagged(acc, rowp, 1u, 0);
      } else {
        mm_plain(acc, reinterpret_cast<const bf16x8*>(xb) + (size_t)(rt * 16 + lr) * 128 + lq);
      }
      store_x(acc, 0);
      seq_pub(&xseq[rt], 1u, l);
    }

    for (int t = 0; t < SEQ; ++t) {
      if (t + 1 < SEQ) {
        seq_wait(&hseq[rt], (unsigned)t);   // pair h-wave consumed buf (t+1)&1
        f32x4 acc[2][4] = {};
        if (layer) {
          const u64* rowp = h1t + (size_t)((t + 1) % RD) * SLOT
                            + (size_t)(rt * 16 + lr) * 512 + lq * 4;
          mm_tagged(acc, rowp, (unsigned)(t + 2), 0);
        } else {
          mm_plain(acc, reinterpret_cast<const bf16x8*>(xb)
                        + ((size_t)(t + 1) * 64 + rt * 16 + lr) * 128 + lq);
        }
        store_x(acc, (t + 1) & 1);
        seq_pub(&xseq[rt], (unsigned)(t + 2), l);
      }
      if (layer) {
        // fout copy h2[t-1] -> out (tag-gated, off recurrence critical path)
        if (t > 0) {
          const u64* sp = h2t + (size_t)((t - 1) % RD) * SLOT + (size_t)l * 512 + nb * 4 + rt;
          u64 q; long s2 = 0;
          do { q = gld(sp); } while ((unsigned)(q >> 32) != (unsigned)t && ++s2 < 60000L);
          unsigned pv = (unsigned)q;
          *reinterpret_cast<float2*>(fout + (size_t)l * (SEQ * HID) + (size_t)(t - 1) * HID
                                     + nb * 8 + rt * 2) = make_float2(b2f_lo(pv), b2f_hi(pv));
        }
        // progress publish (backpressure for L0's h1 ring reuse)
        if (l == 0)
          __hip_atomic_store(prog + (nb * 4 + w) * 32, (unsigned)(t + 1),
                             __ATOMIC_RELAXED, __HIP_MEMORY_SCOPE_AGENT);
      }
    }

    // final output column t=511
    if (layer) {
      const u64* sp = h2t + (size_t)(511 % RD) * SLOT + (size_t)l * 512 + nb * 4 + rt;
      u64 q; long s2 = 0;
      do { q = gld(sp); } while ((unsigned)(q >> 32) != 512u && ++s2 < 60000L);
      unsigned pv = (unsigned)q;
      *reinterpret_cast<float2*>(fout + (size_t)l * (SEQ * HID) + (size_t)511 * HID
                                 + nb * 8 + rt * 2) = make_float2(b2f_lo(pv), b2f_hi(pv));
    }
  } else {
    // ================= h-waves (recurrence critical path) =================
    for (int t = 0; t < SEQ; ++t) {
      // backpressure: before overwriting h1 slot t%RD, ensure L1 consumed t-8
      if (layer == 0 && t >= RD && (t & 3) == 0) {
        unsigned tgt = (unsigned)(t - 4);
        long sp = 0;
        for (;;) {
          bool ok = true;
#pragma unroll
          for (int j = 0; j < 8; ++j) {
            unsigned v = __hip_atomic_load(prog + (l * 8 + j) * 32,
                                           __ATOMIC_RELAXED, __HIP_MEMORY_SCOPE_AGENT);
            ok &= (v >= tgt);
          }
          if (__all(ok)) break;
          if (++sp > 60000L) break;
        }
        asm volatile("" ::: "memory");
      }

      seq_wait(&xseq[rt], (unsigned)(t + 1));   // x buf for step t ready
      const int bn = t & 1;
      f32x4 acc[2][4];
#pragma unroll
      for (int ct = 0; ct < 2; ++ct) {
        acc[ct][0] = f32x4{x_lds[bn][rt][ct * 4 + 0][l], x_lds[bn][rt][ct * 4 + 1][l],
                           x_lds[bn][rt][ct * 4 + 2][l], x_lds[bn][rt][ct * 4 + 3][l]};
        acc[ct][1] = f32x4{0.f, 0.f, 0.f, 0.f};
        acc[ct][2] = f32x4{0.f, 0.f, 0.f, 0.f};
        acc[ct][3] = f32x4{0.f, 0.f, 0.f, 0.f};
      }
      seq_pub(&hseq[rt], (unsigned)(t + 1), l);   // buf consumed

      if (t > 0) {
        const u64* rowp = hring + (size_t)((t - 1) % RD) * SLOT
                          + (size_t)(rt * 16 + lr) * 512 + lq * 4;
        mm_tagged(acc, rowp, (unsigned)t, 2048);
      }

      // ---- in-register epilogue (r5-validated mapping) ----
      f32x4 s0 = (acc[0][0] + acc[0][1]) + (acc[0][2] + acc[0][3]);
      f32x4 s1 = (acc[1][0] + acc[1][1]) + (acc[1][2] + acc[1][3]);
      float a0[4] = {s0.x, s0.y, s0.z, s0.w};   // tile0: i (lr<8) / f (lr>=8)
      float a1[4] = {s1.x, s1.y, s1.z, s1.w};   // tile1: g (lr<8) / o (lr>=8)
      float b0r[4], b1r[4];
#pragma unroll
      for (int r = 0; r < 4; ++r) {
        b0r[r] = __shfl_xor(a0[r], 8, 64);
        b1r[r] = __shfl_xor(a1[r], 8, 64);
      }
      const bool isX = ((l & 8) == 0);
      float hvf[4];
#pragma unroll
      for (int r = 0; r < 4; ++r) {
        float gi = isX ? a0[r] : b0r[r];
        float gf = isX ? b0r[r] : a0[r];
        float gg = isX ? a1[r] : b1r[r];
        float go = isX ? b1r[r] : a1[r];
        float ig = 1.f / (1.f + __expf(-gi));
        float fg = 1.f / (1.f + __expf(-gf));
        float e2 = __expf(2.f * gg);
        float gv = (e2 - 1.f) / (e2 + 1.f);
        float og = 1.f / (1.f + __expf(-go));
        cst[r] = fg * cst[r] + ig * gv;
        float e2c = __expf(2.f * cst[r]);
        hvf[r] = og * (e2c - 1.f) / (e2c + 1.f);
      }
      float hn[4];
#pragma unroll
      for (int r = 0; r < 4; ++r) hn[r] = __shfl_xor(hvf[r], 1, 64);
      const bool ev = ((l & 1) == 0);
      unsigned pk[4];
#pragma unroll
      for (int r = 0; r < 4; ++r) {
        float he = ev ? hvf[r] : hn[r];
        float ho = ev ? hn[r] : hvf[r];
        pk[r] = (unsigned)f2b(he) | ((unsigned)f2b(ho) << 16);
      }
      const int sub = ((l >> 3) & 1) * 2 + (l & 1);
      unsigned pks = sub == 0 ? pk[0] : sub == 1 ? pk[1] : sub == 2 ? pk[2] : pk[3];
      const int row = rt * 16 + lq * 4 + sub;
      const int cp  = (lr & 7) >> 1;
      u64 val = ((u64)(unsigned)(t + 1) << 32) | (u64)pks;
      __hip_atomic_store(hring + (size_t)(t % RD) * SLOT + (size_t)row * 512 + nb * 4 + cp,
                         val, __ATOMIC_RELAXED, __HIP_MEMORY_SCOPE_AGENT);
      // publish IS the store — no drain, no flags, no barrier
    }
  }
}

extern "C" void kernel_launch(void* const* d_in, const int* in_sizes, int n_in,
                              void* d_out, int out_size, void* d_ws, size_t ws_size,
                              hipStream_t stream) {
  const float* x   = (const float*)d_in[0];
  const float* Wx0 = (const float*)d_in[1];
  const float* Wh0 = (const float*)d_in[2];
  const float* b0  = (const float*)d_in[3];
  const float* Wx1 = (const float*)d_in[4];
  const float* Wh1 = (const float*)d_in[5];
  const float* b1  = (const float*)d_in[6];
  float* out = (float*)d_out;
  char* ws = (char*)d_ws;

  unsigned short* xb   = (unsigned short*)(ws);                  // 64 MB
  unsigned short* WxT0 = (unsigned short*)(ws + 67108864);       // 8 MB each
  unsigned short* WhT0 = (unsigned short*)(ws + 75497472);
  unsigned short* WxT1 = (unsigned short*)(ws + 83886080);
  unsigned short* WhT1 = (unsigned short*)(ws + 92274688);
  u64* h1t             = (u64*)(ws + 100663296);                 // 2 MB tagged ring
  u64* h2t             = (u64*)(ws + 102760448);                 // 2 MB tagged ring
  unsigned* prog       = (unsigned*)(ws + 104857600);            // 64 KB

  // clear rings + progress each call (replay-safe; no cross-call state)
  hipMemsetAsync(ws + 100663296, 0, 4259840, stream);
  k_castx<<<32768, 256, 0, stream>>>(x, xb);
  k_wtrans<<<4096, 256, 0, stream>>>(Wx0, WxT0);
  k_wtrans<<<4096, 256, 0, stream>>>(Wh0, WhT0);
  k_wtrans<<<4096, 256, 0, stream>>>(Wx1, WxT1);
  k_wtrans<<<4096, 256, 0, stream>>>(Wh1, WhT1);
  k_scan2<<<2 * NBLK, 512, 0, stream>>>(xb, WxT0, WhT0, b0, WxT1, WhT1, b1,
                                        h1t, h2t, prog, out);
}

// Round 9
// 5208.574 us; speedup vs baseline: 3.3791x; 3.3791x over previous
//
#include <hip/hip_runtime.h>
#include <hip/hip_bf16.h>

#define SEQ  512
#define HID  1024
#define G4   4096
#define NBLK 128   // blocks per layer; grid = 256

typedef short bf16x8 __attribute__((ext_vector_type(8)));
typedef float f32x4  __attribute__((ext_vector_type(4)));
typedef unsigned long long u64;

static __device__ __forceinline__ unsigned short f2b(float f) {
  union { float f; unsigned u; } v; v.f = f;
  unsigned r = (v.u + 0x7FFFu + ((v.u >> 16) & 1u)) >> 16;  // RNE
  return (unsigned short)r;
}
static __device__ __forceinline__ float b2f_lo(unsigned u) {
  union { unsigned u; float f; } v; v.u = u << 16; return v.f;
}
static __device__ __forceinline__ float b2f_hi(unsigned u) {
  union { unsigned u; float f; } v; v.u = u & 0xFFFF0000u; return v.f;
}

// x (B,S,I) f32 -> xb row-major (S*B, I) bf16, row r = s*64+b
__global__ __launch_bounds__(256) void k_castx(const float* __restrict__ x,
                                               unsigned short* __restrict__ xb) {
  int idx = blockIdx.x * 256 + threadIdx.x;
  int r = idx >> 8, kq = idx & 255;
  int b = r & 63, s = r >> 6;
  float4 v = *reinterpret_cast<const float4*>(x + ((size_t)b * SEQ + s) * HID + (size_t)kq * 4);
  ushort4 o;
  o.x = f2b(v.x); o.y = f2b(v.y); o.z = f2b(v.z); o.w = f2b(v.w);
  *reinterpret_cast<ushort4*>(xb + (size_t)r * HID + kq * 4) = o;
}

// W (K=1024, N=4096) f32 -> WT (N=4096, K=1024) bf16
__global__ __launch_bounds__(256) void k_wtrans(const float* __restrict__ W,
                                                unsigned short* __restrict__ WT) {
  __shared__ float tls[32][33];
  int tile = blockIdx.x;
  int nt = tile & 127, kt = tile >> 7;
  int tx = threadIdx.x & 31, ty = threadIdx.x >> 5;
  int k0 = kt * 32, n0 = nt * 32;
  for (int i = 0; i < 4; ++i)
    tls[ty + 8 * i][tx] = W[(size_t)(k0 + ty + 8 * i) * G4 + n0 + tx];
  __syncthreads();
  for (int i = 0; i < 4; ++i)
    WT[(size_t)(n0 + ty + 8 * i) * HID + k0 + tx] = f2b(tls[tx][ty + 8 * i]);
}

// Poll 128 per-block flag words (128B apart, single-writer each, no RMW).
static __device__ __forceinline__ void poll_flags128(unsigned* flags, unsigned tgt) {
  const int l = threadIdx.x & 63;
  unsigned* p0 = flags + l * 32;
  unsigned* p1 = flags + (64 + l) * 32;
  long sp = 0;
  for (;;) {
    unsigned v0 = __hip_atomic_load(p0, __ATOMIC_RELAXED, __HIP_MEMORY_SCOPE_AGENT);
    unsigned v1 = __hip_atomic_load(p1, __ATOMIC_RELAXED, __HIP_MEMORY_SCOPE_AGENT);
    if (__all((v0 >= tgt) && (v1 >= tgt))) break;
    if (++sp > 2000000L) break;   // bailout: wrong answer beats a hang
    __builtin_amdgcn_s_sleep(1);
  }
  asm volatile("" ::: "memory");
}

static __device__ __forceinline__ void lds_wait_u(unsigned* f, unsigned tgt) {
  long sp = 0;
  while (__hip_atomic_load(f, __ATOMIC_ACQUIRE, __HIP_MEMORY_SCOPE_WORKGROUP) < tgt) {
    if (++sp > 50000000L) break;
  }
  asm volatile("" ::: "memory");
}
// publish LDS seq counter after all prior LDS ops completed
static __device__ __forceinline__ void seq_pub(unsigned* p, unsigned v, int lane) {
  asm volatile("s_waitcnt lgkmcnt(0)" ::: "memory");
  if (lane == 0)
    __hip_atomic_store(p, v, __ATOMIC_RELAXED, __HIP_MEMORY_SCOPE_WORKGROUP);
}

// Both LSTM layers, one persistent launch. Blocks 0-127 layer0, 128-255 layer1.
// r9 = r5 skeleton with: NO per-step __syncthreads (x<->h wave pairs hand
// x_lds buffers via monotonic LDS seq counters); fout on L1 x-waves (own-block
// columns, gated by block-local arrival counter); flag published directly by
// the last-arriving h-wave. h-wave vmcnt(0) drains exactly one 4B store.
__global__ __launch_bounds__(512, 1) void k_scan2(
    const unsigned short* __restrict__ xb,
    const unsigned short* __restrict__ WxT0, const unsigned short* __restrict__ WhT0,
    const float* __restrict__ b0,
    const unsigned short* __restrict__ WxT1, const unsigned short* __restrict__ WhT1,
    const float* __restrict__ b1,
    unsigned short* __restrict__ h1,
    unsigned short* __restrict__ h2, int h2mod,
    float* __restrict__ out,
    unsigned* __restrict__ bars) {
  __shared__ unsigned short wlds[32 * 2048];   // 128 KB weights [c][k], swizzled
  __shared__ float x_lds[2][4][8][64];         // x-partials in raw MFMA layout
  __shared__ unsigned lds_arr;                 // h-wave arrivals (monotonic)
  __shared__ unsigned xseq[4], hseq[4];        // x_lds handoff counters
  __shared__ unsigned hrdy, xrdy;              // poller-wave relays (monotonic)

  const int bk  = blockIdx.x;
  const int layer = bk >> 7;
  const int nb  = bk & 127;
  const int tid = threadIdx.x;
  const int w   = tid >> 6;
  const int l   = tid & 63;
  const int lq  = l >> 4, lr = l & 15;
  const int rt  = w & 3;
  const bool is_h = (w >= 4);

  const unsigned short* WxT = layer ? WxT1 : WxT0;
  const unsigned short* WhT = layer ? WhT1 : WhT0;
  const float* bias = layer ? b1 : b0;
  const unsigned short* aseq = layer ? h1 : xb;
  unsigned short* hout = layer ? h2 : h1;
  const int hmod = layer ? h2mod : 512;
  float* fout = layer ? out : nullptr;
  unsigned* ownflags = bars + layer * 4096;    // my layer's 128 flag words
  unsigned* l0flags  = bars;                   // layer0 flags
  unsigned* myflag   = ownflags + nb * 32;     // this block's word (128B apart)

  if (tid == 0) { lds_arr = 0; hrdy = 0; xrdy = 0; }
  if (tid < 4) { xseq[tid] = 0; hseq[tid] = 0; }

  // ---- one-time: stage weight slice into LDS (swizzled byte addr) ----
  {
    int c = tid >> 4, seg = tid & 15;
    int gate = c >> 3, nl = c & 7;
    int gcol = gate * 1024 + nb * 8 + nl;
    const unsigned short* sx = WxT + (size_t)gcol * HID;
    const unsigned short* sh = WhT + (size_t)gcol * HID;
    for (int j = 0; j < 16; ++j) {
      int kk = seg * 128 + j * 8;
      const unsigned short* src = (kk < 1024) ? (sx + kk) : (sh + kk - 1024);
      uint4 v = *reinterpret_cast<const uint4*>(src);
      int db = (c * 4096 + kk * 2) ^ ((c & 7) << 4);
      *reinterpret_cast<uint4*>(reinterpret_cast<char*>(wlds) + db) = v;
    }
  }

  char* wbase = reinterpret_cast<char*>(wlds);
  const int csw = (lr & 7) << 4;
  const int cb0 = (lr) * 4096 + lq * 16;
  const int cb1 = (16 + lr) * 4096 + lq * 16;

  float bias_c[2];
#pragma unroll
  for (int ct = 0; ct < 2; ++ct) {
    int col = ct * 16 + lr;
    bias_c[ct] = bias[(col >> 3) * 1024 + nb * 8 + (col & 7)];
  }

  float cst[4] = {0.f, 0.f, 0.f, 0.f};   // c-state: 4 rows x 1 col per lane

  __syncthreads();
  if (is_h) __builtin_amdgcn_s_setprio(1);

  if (!is_h) {
    // ================= x-waves =================
    // prologue: projection for step 0 into buf0
    {
      if (layer) poll_flags128(l0flags, 1u);     // h1[0] complete
      const bf16x8* ax = reinterpret_cast<const bf16x8*>(aseq) + (size_t)(rt * 16 + lr) * 128 + lq;
      f32x4 acc[2][4] = {};
#pragma unroll 8
      for (int ks = 0; ks < 32; ++ks) {
        bf16x8 a  = ax[ks * 4];
        bf16x8 bb0 = *reinterpret_cast<const bf16x8*>(wbase + ((cb0 + ks * 64) ^ csw));
        bf16x8 bb1 = *reinterpret_cast<const bf16x8*>(wbase + ((cb1 + ks * 64) ^ csw));
        acc[0][ks & 3] = __builtin_amdgcn_mfma_f32_16x16x32_bf16(a, bb0, acc[0][ks & 3], 0, 0, 0);
        acc[1][ks & 3] = __builtin_amdgcn_mfma_f32_16x16x32_bf16(a, bb1, acc[1][ks & 3], 0, 0, 0);
      }
#pragma unroll
      for (int ct = 0; ct < 2; ++ct) {
        f32x4 s = (acc[ct][0] + acc[ct][1]) + (acc[ct][2] + acc[ct][3]);
        float bc = bias_c[ct];
        x_lds[0][rt][ct * 4 + 0][l] = s.x + bc;
        x_lds[0][rt][ct * 4 + 1][l] = s.y + bc;
        x_lds[0][rt][ct * 4 + 2][l] = s.z + bc;
        x_lds[0][rt][ct * 4 + 3][l] = s.w + bc;
      }
      seq_pub(&xseq[rt], 1u, l);
    }

    for (int t = 0; t < SEQ; ++t) {
      // ---------- project input of step t+1 into x_lds[(t+1)&1] ----------
      if (t + 1 < SEQ) {
        if (layer) {
          if (w == 0) {
            poll_flags128(l0flags, (unsigned)(t + 2));   // h1[t+1] complete
            __hip_atomic_store(&xrdy, (unsigned)(t + 1), __ATOMIC_RELAXED,
                               __HIP_MEMORY_SCOPE_WORKGROUP);
          } else {
            lds_wait_u(&xrdy, (unsigned)(t + 1));
          }
        }
        lds_wait_u(&hseq[rt], (unsigned)t);   // pair h-wave done with this buffer
        const bf16x8* ax = reinterpret_cast<const bf16x8*>(aseq)
                           + ((size_t)(t + 1) * 64 + rt * 16 + lr) * 128 + lq;
        f32x4 acc[2][4] = {};
#pragma unroll 8
        for (int ks = 0; ks < 32; ++ks) {
          bf16x8 a  = ax[ks * 4];
          bf16x8 bb0 = *reinterpret_cast<const bf16x8*>(wbase + ((cb0 + ks * 64) ^ csw));
          bf16x8 bb1 = *reinterpret_cast<const bf16x8*>(wbase + ((cb1 + ks * 64) ^ csw));
          acc[0][ks & 3] = __builtin_amdgcn_mfma_f32_16x16x32_bf16(a, bb0, acc[0][ks & 3], 0, 0, 0);
          acc[1][ks & 3] = __builtin_amdgcn_mfma_f32_16x16x32_bf16(a, bb1, acc[1][ks & 3], 0, 0, 0);
        }
        int bn2 = (t + 1) & 1;
#pragma unroll
        for (int ct = 0; ct < 2; ++ct) {
          f32x4 s = (acc[ct][0] + acc[ct][1]) + (acc[ct][2] + acc[ct][3]);
          float bc = bias_c[ct];
          x_lds[bn2][rt][ct * 4 + 0][l] = s.x + bc;
          x_lds[bn2][rt][ct * 4 + 1][l] = s.y + bc;
          x_lds[bn2][rt][ct * 4 + 2][l] = s.z + bc;
          x_lds[bn2][rt][ct * 4 + 3][l] = s.w + bc;
        }
        seq_pub(&xseq[rt], (unsigned)(t + 2), l);
      }
      // ---------- L1 x-waves: copy own-block cols of h2[t-1] -> fout ----------
      if (fout && t > 0) {
        lds_wait_u(&lds_arr, 4u * (unsigned)t);   // own h-waves finished t-1
        const unsigned* sp32 = reinterpret_cast<const unsigned*>(
            hout + (size_t)((t - 1) % hmod) * (64 * HID)) + (size_t)l * 512 + nb * 4 + rt;
        unsigned pv = __hip_atomic_load(sp32, __ATOMIC_RELAXED, __HIP_MEMORY_SCOPE_AGENT);
        *reinterpret_cast<float2*>(fout + (size_t)l * (SEQ * HID) + (size_t)(t - 1) * HID
                                   + nb * 8 + rt * 2) = make_float2(b2f_lo(pv), b2f_hi(pv));
      }
    }
    // final output column t=511
    if (fout) {
      lds_wait_u(&lds_arr, 4u * (unsigned)SEQ);
      const unsigned* sp32 = reinterpret_cast<const unsigned*>(
          hout + (size_t)(511 % hmod) * (64 * HID)) + (size_t)l * 512 + nb * 4 + rt;
      unsigned pv = __hip_atomic_load(sp32, __ATOMIC_RELAXED, __HIP_MEMORY_SCOPE_AGENT);
      *reinterpret_cast<float2*>(fout + (size_t)l * (SEQ * HID) + (size_t)511 * HID
                                 + nb * 8 + rt * 2) = make_float2(b2f_lo(pv), b2f_hi(pv));
    }
  } else {
    // ================= h-waves (recurrence critical path) =================
    for (int t = 0; t < SEQ; ++t) {
      lds_wait_u(&xseq[rt], (unsigned)(t + 1));   // x buf for step t ready
      const int bn = t & 1;
      f32x4 acc[2][4];
#pragma unroll
      for (int ct = 0; ct < 2; ++ct) {
        acc[ct][0] = f32x4{x_lds[bn][rt][ct * 4 + 0][l], x_lds[bn][rt][ct * 4 + 1][l],
                           x_lds[bn][rt][ct * 4 + 2][l], x_lds[bn][rt][ct * 4 + 3][l]};
        acc[ct][1] = f32x4{0.f, 0.f, 0.f, 0.f};
        acc[ct][2] = f32x4{0.f, 0.f, 0.f, 0.f};
        acc[ct][3] = f32x4{0.f, 0.f, 0.f, 0.f};
      }
      seq_pub(&hseq[rt], (unsigned)(t + 1), l);   // buffer consumed

      if (t > 0) {
        if (w == 4) {
          poll_flags128(ownflags, (unsigned)t);   // all blocks finished t-1
          __hip_atomic_store(&hrdy, (unsigned)t, __ATOMIC_RELAXED,
                             __HIP_MEMORY_SCOPE_WORKGROUP);
        } else {
          lds_wait_u(&hrdy, (unsigned)t);
        }
        const size_t hbase = (size_t)((t - 1) % hmod) * (64 * HID) + (size_t)(rt * 16 + lr) * HID;
        if (hmod != 4) {
          const bf16x8* hp = reinterpret_cast<const bf16x8*>(hout + hbase) + lq;
#pragma unroll 8
          for (int ks = 0; ks < 32; ++ks) {
            bf16x8 a = hp[ks * 4];
            bf16x8 bb0 = *reinterpret_cast<const bf16x8*>(wbase + ((cb0 + 2048 + ks * 64) ^ csw));
            bf16x8 bb1 = *reinterpret_cast<const bf16x8*>(wbase + ((cb1 + 2048 + ks * 64) ^ csw));
            acc[0][ks & 3] = __builtin_amdgcn_mfma_f32_16x16x32_bf16(a, bb0, acc[0][ks & 3], 0, 0, 0);
            acc[1][ks & 3] = __builtin_amdgcn_mfma_f32_16x16x32_bf16(a, bb1, acc[1][ks & 3], 0, 0, 0);
          }
        } else {
          const u64* hp = reinterpret_cast<const u64*>(hout + hbase) + lq * 2;
#pragma unroll 8
          for (int ks = 0; ks < 32; ++ks) {
            u64 q0 = __hip_atomic_load(hp + ks * 8,     __ATOMIC_RELAXED, __HIP_MEMORY_SCOPE_AGENT);
            u64 q1 = __hip_atomic_load(hp + ks * 8 + 1, __ATOMIC_RELAXED, __HIP_MEMORY_SCOPE_AGENT);
            union { u64 q[2]; bf16x8 v; } u; u.q[0] = q0; u.q[1] = q1;
            bf16x8 bb0 = *reinterpret_cast<const bf16x8*>(wbase + ((cb0 + 2048 + ks * 64) ^ csw));
            bf16x8 bb1 = *reinterpret_cast<const bf16x8*>(wbase + ((cb1 + 2048 + ks * 64) ^ csw));
            acc[0][ks & 3] = __builtin_amdgcn_mfma_f32_16x16x32_bf16(u.v, bb0, acc[0][ks & 3], 0, 0, 0);
            acc[1][ks & 3] = __builtin_amdgcn_mfma_f32_16x16x32_bf16(u.v, bb1, acc[1][ks & 3], 0, 0, 0);
          }
        }
      }

      // ---- in-register epilogue (r5-validated mapping) ----
      f32x4 s0 = (acc[0][0] + acc[0][1]) + (acc[0][2] + acc[0][3]);
      f32x4 s1 = (acc[1][0] + acc[1][1]) + (acc[1][2] + acc[1][3]);
      float a0[4] = {s0.x, s0.y, s0.z, s0.w};   // tile0: i (lr<8) / f (lr>=8)
      float a1[4] = {s1.x, s1.y, s1.z, s1.w};   // tile1: g (lr<8) / o (lr>=8)
      float b0r[4], b1r[4];
#pragma unroll
      for (int r = 0; r < 4; ++r) {
        b0r[r] = __shfl_xor(a0[r], 8, 64);
        b1r[r] = __shfl_xor(a1[r], 8, 64);
      }
      const bool isX = ((l & 8) == 0);
      float hvf[4];
#pragma unroll
      for (int r = 0; r < 4; ++r) {
        float gi = isX ? a0[r] : b0r[r];
        float gf = isX ? b0r[r] : a0[r];
        float gg = isX ? a1[r] : b1r[r];
        float go = isX ? b1r[r] : a1[r];
        float ig = 1.f / (1.f + __expf(-gi));
        float fg = 1.f / (1.f + __expf(-gf));
        float e2 = __expf(2.f * gg);
        float gv = (e2 - 1.f) / (e2 + 1.f);
        float og = 1.f / (1.f + __expf(-go));
        cst[r] = fg * cst[r] + ig * gv;
        float e2c = __expf(2.f * cst[r]);
        hvf[r] = og * (e2c - 1.f) / (e2c + 1.f);
      }
      float hn[4];
#pragma unroll
      for (int r = 0; r < 4; ++r) hn[r] = __shfl_xor(hvf[r], 1, 64);
      const bool ev = ((l & 1) == 0);
      unsigned pk[4];
#pragma unroll
      for (int r = 0; r < 4; ++r) {
        float he = ev ? hvf[r] : hn[r];
        float ho = ev ? hn[r] : hvf[r];
        pk[r] = (unsigned)f2b(he) | ((unsigned)f2b(ho) << 16);
      }
      const int sub = ((l >> 3) & 1) * 2 + (l & 1);
      unsigned pks = sub == 0 ? pk[0] : sub == 1 ? pk[1] : sub == 2 ? pk[2] : pk[3];
      const int row = rt * 16 + lq * 4 + sub;
      const int cp  = (lr & 7) >> 1;
      unsigned* hw = reinterpret_cast<unsigned*>(hout + (size_t)(t % hmod) * (64 * HID))
                     + (size_t)row * 512 + nb * 4 + cp;
      __hip_atomic_store(hw, pks, __ATOMIC_RELAXED, __HIP_MEMORY_SCOPE_AGENT);

      // drain own 4B store, then last-arriving wave publishes the block flag
      asm volatile("s_waitcnt vmcnt(0)" ::: "memory");
      if (l == 0) {
        unsigned pb = atomicAdd(&lds_arr, 1u);
        if ((pb & 3) == 3)
          __hip_atomic_store(myflag, (pb >> 2) + 1u, __ATOMIC_RELAXED,
                             __HIP_MEMORY_SCOPE_AGENT);
      }
    }
  }
}

extern "C" void kernel_launch(void* const* d_in, const int* in_sizes, int n_in,
                              void* d_out, int out_size, void* d_ws, size_t ws_size,
                              hipStream_t stream) {
  const float* x   = (const float*)d_in[0];
  const float* Wx0 = (const float*)d_in[1];
  const float* Wh0 = (const float*)d_in[2];
  const float* b0  = (const float*)d_in[3];
  const float* Wx1 = (const float*)d_in[4];
  const float* Wh1 = (const float*)d_in[5];
  const float* b1  = (const float*)d_in[6];
  float* out = (float*)d_out;
  char* ws = (char*)d_ws;

  unsigned short* xb   = (unsigned short*)(ws);                  // 64 MB
  unsigned short* h1   = (unsigned short*)(ws + 67108864);       // 64 MB
  unsigned short* WxT0 = (unsigned short*)(ws + 134217728);      // 8 MB each
  unsigned short* WhT0 = (unsigned short*)(ws + 142606336);
  unsigned short* WxT1 = (unsigned short*)(ws + 150994944);
  unsigned short* WhT1 = (unsigned short*)(ws + 159383552);
  unsigned* bars       = (unsigned*)(ws + 167772160);            // 32 KB flags
  unsigned short* h2   = (unsigned short*)(ws + 167804928);
  int h2mod = (ws_size >= (size_t)167804928 + 67108864) ? 512 : 4;

  hipMemsetAsync(bars, 0, 32768, stream);
  k_castx<<<32768, 256, 0, stream>>>(x, xb);
  k_wtrans<<<4096, 256, 0, stream>>>(Wx0, WxT0);
  k_wtrans<<<4096, 256, 0, stream>>>(Wh0, WhT0);
  k_wtrans<<<4096, 256, 0, stream>>>(Wx1, WxT1);
  k_wtrans<<<4096, 256, 0, stream>>>(Wh1, WhT1);
  k_scan2<<<2 * NBLK, 512, 0, stream>>>(xb, WxT0, WhT0, b0, WxT1, WhT1, b1,
                                        h1, h2, h2mod, out, bars);
}

// Round 11
// 5183.364 us; speedup vs baseline: 3.3955x; 1.0049x over previous
//
#include <hip/hip_runtime.h>
#include <hip/hip_bf16.h>

#define SEQ  512
#define HID  1024
#define G4   4096
#define NBLK 128   // blocks per layer; grid = 256

typedef short bf16x8 __attribute__((ext_vector_type(8)));
typedef float f32x4  __attribute__((ext_vector_type(4)));
typedef float f32x2  __attribute__((ext_vector_type(2)));
typedef unsigned short usx4 __attribute__((ext_vector_type(4)));
typedef unsigned long long u64;

static __device__ __forceinline__ unsigned short f2b(float f) {
  union { float f; unsigned u; } v; v.f = f;
  unsigned r = (v.u + 0x7FFFu + ((v.u >> 16) & 1u)) >> 16;  // RNE
  return (unsigned short)r;
}
static __device__ __forceinline__ float b2f_lo(unsigned u) {
  union { unsigned u; float f; } v; v.u = u << 16; return v.f;
}
static __device__ __forceinline__ float b2f_hi(unsigned u) {
  union { unsigned u; float f; } v; v.u = u & 0xFFFF0000u; return v.f;
}

// x (B,S,I) f32 -> xb row-major (S*B, I) bf16, row r = s*64+b
// nt on both sides: x is read once, xb is a stream consumed once by the scan.
__global__ __launch_bounds__(256) void k_castx(const float* __restrict__ x,
                                               unsigned short* __restrict__ xb) {
  int idx = blockIdx.x * 256 + threadIdx.x;
  int r = idx >> 8, kq = idx & 255;
  int b = r & 63, s = r >> 6;
  const f32x4* src = reinterpret_cast<const f32x4*>(x + ((size_t)b * SEQ + s) * HID + (size_t)kq * 4);
  f32x4 v = __builtin_nontemporal_load(src);
  usx4 o;
  o.x = f2b(v.x); o.y = f2b(v.y); o.z = f2b(v.z); o.w = f2b(v.w);
  __builtin_nontemporal_store(o, reinterpret_cast<usx4*>(xb + (size_t)r * HID + kq * 4));
}

// W (K=1024, N=4096) f32 -> WT (N=4096, K=1024) bf16
__global__ __launch_bounds__(256) void k_wtrans(const float* __restrict__ W,
                                                unsigned short* __restrict__ WT) {
  __shared__ float tls[32][33];
  int tile = blockIdx.x;
  int nt = tile & 127, kt = tile >> 7;
  int tx = threadIdx.x & 31, ty = threadIdx.x >> 5;
  int k0 = kt * 32, n0 = nt * 32;
  for (int i = 0; i < 4; ++i)
    tls[ty + 8 * i][tx] = W[(size_t)(k0 + ty + 8 * i) * G4 + n0 + tx];
  __syncthreads();
  for (int i = 0; i < 4; ++i)
    WT[(size_t)(n0 + ty + 8 * i) * HID + k0 + tx] = f2b(tls[tx][ty + 8 * i]);
}

// Poll 128 per-block flag words (128B apart, single-writer each, no RMW).
static __device__ __forceinline__ void poll_flags128(unsigned* flags, unsigned tgt) {
  const int l = threadIdx.x & 63;
  unsigned* p0 = flags + l * 32;
  unsigned* p1 = flags + (64 + l) * 32;
  long sp = 0;
  for (;;) {
    unsigned v0 = __hip_atomic_load(p0, __ATOMIC_RELAXED, __HIP_MEMORY_SCOPE_AGENT);
    unsigned v1 = __hip_atomic_load(p1, __ATOMIC_RELAXED, __HIP_MEMORY_SCOPE_AGENT);
    if (__all((v0 >= tgt) && (v1 >= tgt))) break;
    if (++sp > 2000000L) break;   // bailout: wrong answer beats a hang
    __builtin_amdgcn_s_sleep(1);
  }
  asm volatile("" ::: "memory");
}

static __device__ __forceinline__ void lds_wait(int* f, int tgt) {
  long sp = 0;
  while (__hip_atomic_load(f, __ATOMIC_RELAXED, __HIP_MEMORY_SCOPE_WORKGROUP) < tgt) {
    if (++sp > 50000000L) break;
    __builtin_amdgcn_s_sleep(1);
  }
  asm volatile("" ::: "memory");
}

// r10 = r5 skeleton (best measured: 4.79 ms) + cache-policy isolation:
// x path and fout are non-temporal streams so the h-rings + weights
// (~160 MB) stay L3-resident and the per-step h-broadcast never misses to HBM.
__global__ __launch_bounds__(512, 1) void k_scan2(
    const unsigned short* __restrict__ xb,
    const unsigned short* __restrict__ WxT0, const unsigned short* __restrict__ WhT0,
    const float* __restrict__ b0,
    const unsigned short* __restrict__ WxT1, const unsigned short* __restrict__ WhT1,
    const float* __restrict__ b1,
    unsigned short* __restrict__ h1,
    unsigned short* __restrict__ h2, int h2mod,
    float* __restrict__ out,
    unsigned* __restrict__ bars) {
  __shared__ unsigned short wlds[32 * 2048];   // 128 KB weights [c][k], swizzled
  __shared__ float x_lds[2][4][8][64];         // x-partials in raw MFMA layout
  __shared__ unsigned lds_arr;
  __shared__ int hrdy, xrdy;

  const int bk  = blockIdx.x;
  const int layer = bk >> 7;
  const int nb  = bk & 127;
  const int tid = threadIdx.x;
  const int w   = tid >> 6;
  const int l   = tid & 63;
  const int lq  = l >> 4, lr = l & 15;
  const int rt  = w & 3;
  const bool is_h = (w >= 4);

  const unsigned short* WxT = layer ? WxT1 : WxT0;
  const unsigned short* WhT = layer ? WhT1 : WhT0;
  const float* bias = layer ? b1 : b0;
  const unsigned short* aseq = layer ? h1 : xb;
  unsigned short* hout = layer ? h2 : h1;
  const int hmod = layer ? h2mod : 512;
  float* fout = layer ? out : nullptr;
  unsigned* ownflags = bars + layer * 4096;    // my layer's 128 flag words
  unsigned* l0flags  = bars;                   // layer0 flags
  unsigned* myflag   = ownflags + nb * 32;     // this block's word (128B apart)

  if (tid == 0) { lds_arr = 0; hrdy = 0; xrdy = 0; }

  // ---- one-time: stage weight slice into LDS (swizzled byte addr) ----
  {
    int c = tid >> 4, seg = tid & 15;
    int gate = c >> 3, nl = c & 7;
    int gcol = gate * 1024 + nb * 8 + nl;
    const unsigned short* sx = WxT + (size_t)gcol * HID;
    const unsigned short* sh = WhT + (size_t)gcol * HID;
    for (int j = 0; j < 16; ++j) {
      int kk = seg * 128 + j * 8;
      const unsigned short* src = (kk < 1024) ? (sx + kk) : (sh + kk - 1024);
      uint4 v = *reinterpret_cast<const uint4*>(src);
      int db = (c * 4096 + kk * 2) ^ ((c & 7) << 4);
      *reinterpret_cast<uint4*>(reinterpret_cast<char*>(wlds) + db) = v;
    }
  }

  char* wbase = reinterpret_cast<char*>(wlds);
  const int csw = (lr & 7) << 4;
  const int cb0 = (lr) * 4096 + lq * 16;
  const int cb1 = (16 + lr) * 4096 + lq * 16;

  float bias_c[2];
#pragma unroll
  for (int ct = 0; ct < 2; ++ct) {
    int col = ct * 16 + lr;
    bias_c[ct] = bias[(col >> 3) * 1024 + nb * 8 + (col & 7)];
  }

  float cst[4] = {0.f, 0.f, 0.f, 0.f};   // c-state: 4 rows x 1 col per lane

  __syncthreads();
  if (is_h) __builtin_amdgcn_s_setprio(1);

  // ---- prologue: x-projection for step 0 into x_lds[0] ----
  if (!is_h) {
    if (layer) poll_flags128(l0flags, 1u);       // h1[0] complete
    const bf16x8* ax = reinterpret_cast<const bf16x8*>(aseq) + (size_t)(rt * 16 + lr) * 128 + lq;
    f32x4 acc[2][4] = {};
    if (layer == 0) {
#pragma unroll 8
      for (int ks = 0; ks < 32; ++ks) {
        bf16x8 a = __builtin_nontemporal_load(ax + ks * 4);
        bf16x8 bb0 = *reinterpret_cast<const bf16x8*>(wbase + ((cb0 + ks * 64) ^ csw));
        bf16x8 bb1 = *reinterpret_cast<const bf16x8*>(wbase + ((cb1 + ks * 64) ^ csw));
        acc[0][ks & 3] = __builtin_amdgcn_mfma_f32_16x16x32_bf16(a, bb0, acc[0][ks & 3], 0, 0, 0);
        acc[1][ks & 3] = __builtin_amdgcn_mfma_f32_16x16x32_bf16(a, bb1, acc[1][ks & 3], 0, 0, 0);
      }
    } else {
#pragma unroll 8
      for (int ks = 0; ks < 32; ++ks) {
        bf16x8 a = ax[ks * 4];
        bf16x8 bb0 = *reinterpret_cast<const bf16x8*>(wbase + ((cb0 + ks * 64) ^ csw));
        bf16x8 bb1 = *reinterpret_cast<const bf16x8*>(wbase + ((cb1 + ks * 64) ^ csw));
        acc[0][ks & 3] = __builtin_amdgcn_mfma_f32_16x16x32_bf16(a, bb0, acc[0][ks & 3], 0, 0, 0);
        acc[1][ks & 3] = __builtin_amdgcn_mfma_f32_16x16x32_bf16(a, bb1, acc[1][ks & 3], 0, 0, 0);
      }
    }
#pragma unroll
    for (int ct = 0; ct < 2; ++ct) {
      f32x4 s = (acc[ct][0] + acc[ct][1]) + (acc[ct][2] + acc[ct][3]);
      float bc = bias_c[ct];
      x_lds[0][w][ct * 4 + 0][l] = s.x + bc;
      x_lds[0][w][ct * 4 + 1][l] = s.y + bc;
      x_lds[0][w][ct * 4 + 2][l] = s.z + bc;
      x_lds[0][w][ct * 4 + 3][l] = s.w + bc;
    }
  }
  __syncthreads();

  for (int t = 0; t < SEQ; ++t) {
    if (!is_h) {
      // ---------- x-waves: project input of step t+1 into x_lds[(t+1)&1] ----------
      if (t + 1 < SEQ) {
        if (layer) {
          if (w == 0) {
            poll_flags128(l0flags, (unsigned)(t + 2));   // h1[t+1] complete
            __hip_atomic_store(&xrdy, t + 1, __ATOMIC_RELAXED, __HIP_MEMORY_SCOPE_WORKGROUP);
          } else {
            lds_wait(&xrdy, t + 1);
          }
        }
        const bf16x8* ax = reinterpret_cast<const bf16x8*>(aseq)
                           + ((size_t)(t + 1) * 64 + rt * 16 + lr) * 128 + lq;
        f32x4 acc[2][4] = {};
        if (layer == 0) {
#pragma unroll 8
          for (int ks = 0; ks < 32; ++ks) {
            bf16x8 a = __builtin_nontemporal_load(ax + ks * 4);
            bf16x8 bb0 = *reinterpret_cast<const bf16x8*>(wbase + ((cb0 + ks * 64) ^ csw));
            bf16x8 bb1 = *reinterpret_cast<const bf16x8*>(wbase + ((cb1 + ks * 64) ^ csw));
            acc[0][ks & 3] = __builtin_amdgcn_mfma_f32_16x16x32_bf16(a, bb0, acc[0][ks & 3], 0, 0, 0);
            acc[1][ks & 3] = __builtin_amdgcn_mfma_f32_16x16x32_bf16(a, bb1, acc[1][ks & 3], 0, 0, 0);
          }
        } else {
#pragma unroll 8
          for (int ks = 0; ks < 32; ++ks) {
            bf16x8 a = ax[ks * 4];
            bf16x8 bb0 = *reinterpret_cast<const bf16x8*>(wbase + ((cb0 + ks * 64) ^ csw));
            bf16x8 bb1 = *reinterpret_cast<const bf16x8*>(wbase + ((cb1 + ks * 64) ^ csw));
            acc[0][ks & 3] = __builtin_amdgcn_mfma_f32_16x16x32_bf16(a, bb0, acc[0][ks & 3], 0, 0, 0);
            acc[1][ks & 3] = __builtin_amdgcn_mfma_f32_16x16x32_bf16(a, bb1, acc[1][ks & 3], 0, 0, 0);
          }
        }
        int bn2 = (t + 1) & 1;
#pragma unroll
        for (int ct = 0; ct < 2; ++ct) {
          f32x4 s = (acc[ct][0] + acc[ct][1]) + (acc[ct][2] + acc[ct][3]);
          float bc = bias_c[ct];
          x_lds[bn2][w][ct * 4 + 0][l] = s.x + bc;
          x_lds[bn2][w][ct * 4 + 1][l] = s.y + bc;
          x_lds[bn2][w][ct * 4 + 2][l] = s.z + bc;
          x_lds[bn2][w][ct * 4 + 3][l] = s.w + bc;
        }
      }
    } else {
      // ---------- h-waves: recurrence critical path ----------
      const int bn = t & 1;
      f32x4 acc[2][4];
#pragma unroll
      for (int ct = 0; ct < 2; ++ct) {
        acc[ct][0] = f32x4{x_lds[bn][rt][ct * 4 + 0][l], x_lds[bn][rt][ct * 4 + 1][l],
                           x_lds[bn][rt][ct * 4 + 2][l], x_lds[bn][rt][ct * 4 + 3][l]};
        acc[ct][1] = f32x4{0.f, 0.f, 0.f, 0.f};
        acc[ct][2] = f32x4{0.f, 0.f, 0.f, 0.f};
        acc[ct][3] = f32x4{0.f, 0.f, 0.f, 0.f};
      }

      if (t > 0) {
        if (w == 4) {
          poll_flags128(ownflags, (unsigned)t);          // all blocks finished t-1
          __hip_atomic_store(&hrdy, t, __ATOMIC_RELAXED, __HIP_MEMORY_SCOPE_WORKGROUP);
        } else {
          lds_wait(&hrdy, t);
        }
        const size_t hbase = (size_t)((t - 1) % hmod) * (64 * HID) + (size_t)(rt * 16 + lr) * HID;
        if (hmod != 4) {
          const bf16x8* hp = reinterpret_cast<const bf16x8*>(hout + hbase) + lq;
#pragma unroll 8
          for (int ks = 0; ks < 32; ++ks) {
            bf16x8 a = hp[ks * 4];
            bf16x8 bb0 = *reinterpret_cast<const bf16x8*>(wbase + ((cb0 + 2048 + ks * 64) ^ csw));
            bf16x8 bb1 = *reinterpret_cast<const bf16x8*>(wbase + ((cb1 + 2048 + ks * 64) ^ csw));
            acc[0][ks & 3] = __builtin_amdgcn_mfma_f32_16x16x32_bf16(a, bb0, acc[0][ks & 3], 0, 0, 0);
            acc[1][ks & 3] = __builtin_amdgcn_mfma_f32_16x16x32_bf16(a, bb1, acc[1][ks & 3], 0, 0, 0);
          }
        } else {
          const u64* hp = reinterpret_cast<const u64*>(hout + hbase) + lq * 2;
#pragma unroll 8
          for (int ks = 0; ks < 32; ++ks) {
            u64 q0 = __hip_atomic_load(hp + ks * 8,     __ATOMIC_RELAXED, __HIP_MEMORY_SCOPE_AGENT);
            u64 q1 = __hip_atomic_load(hp + ks * 8 + 1, __ATOMIC_RELAXED, __HIP_MEMORY_SCOPE_AGENT);
            union { u64 q[2]; bf16x8 v; } u; u.q[0] = q0; u.q[1] = q1;
            bf16x8 bb0 = *reinterpret_cast<const bf16x8*>(wbase + ((cb0 + 2048 + ks * 64) ^ csw));
            bf16x8 bb1 = *reinterpret_cast<const bf16x8*>(wbase + ((cb1 + 2048 + ks * 64) ^ csw));
            acc[0][ks & 3] = __builtin_amdgcn_mfma_f32_16x16x32_bf16(u.v, bb0, acc[0][ks & 3], 0, 0, 0);
            acc[1][ks & 3] = __builtin_amdgcn_mfma_f32_16x16x32_bf16(u.v, bb1, acc[1][ks & 3], 0, 0, 0);
          }
        }
      }

      // ---- in-register epilogue ----
      f32x4 s0 = (acc[0][0] + acc[0][1]) + (acc[0][2] + acc[0][3]);
      f32x4 s1 = (acc[1][0] + acc[1][1]) + (acc[1][2] + acc[1][3]);
      float a0[4] = {s0.x, s0.y, s0.z, s0.w};   // tile0: i (lr<8) / f (lr>=8)
      float a1[4] = {s1.x, s1.y, s1.z, s1.w};   // tile1: g (lr<8) / o (lr>=8)
      float b0r[4], b1r[4];
#pragma unroll
      for (int r = 0; r < 4; ++r) {
        b0r[r] = __shfl_xor(a0[r], 8, 64);
        b1r[r] = __shfl_xor(a1[r], 8, 64);
      }
      const bool isX = ((l & 8) == 0);
      float hvf[4];
#pragma unroll
      for (int r = 0; r < 4; ++r) {
        float gi = isX ? a0[r] : b0r[r];
        float gf = isX ? b0r[r] : a0[r];
        float gg = isX ? a1[r] : b1r[r];
        float go = isX ? b1r[r] : a1[r];
        float ig = 1.f / (1.f + __expf(-gi));
        float fg = 1.f / (1.f + __expf(-gf));
        float e2 = __expf(2.f * gg);
        float gv = (e2 - 1.f) / (e2 + 1.f);
        float og = 1.f / (1.f + __expf(-go));
        cst[r] = fg * cst[r] + ig * gv;
        float e2c = __expf(2.f * cst[r]);
        hvf[r] = og * (e2c - 1.f) / (e2c + 1.f);
      }
      // col-pair packing: lane^1 exchange, then one u32 store per lane
      float hn[4];
#pragma unroll
      for (int r = 0; r < 4; ++r) hn[r] = __shfl_xor(hvf[r], 1, 64);
      const bool ev = ((l & 1) == 0);
      unsigned pk[4]; float he[4], ho[4];
#pragma unroll
      for (int r = 0; r < 4; ++r) {
        he[r] = ev ? hvf[r] : hn[r];
        ho[r] = ev ? hn[r] : hvf[r];
        pk[r] = (unsigned)f2b(he[r]) | ((unsigned)f2b(ho[r]) << 16);
      }
      const int sub = ((l >> 3) & 1) * 2 + (l & 1);     // 0..3: which row I store
      unsigned pks = sub == 0 ? pk[0] : sub == 1 ? pk[1] : sub == 2 ? pk[2] : pk[3];
      const int row = rt * 16 + lq * 4 + sub;
      const int cp  = (lr & 7) >> 1;
      unsigned* hw = reinterpret_cast<unsigned*>(hout + (size_t)(t % hmod) * (64 * HID))
                     + (size_t)row * 512 + nb * 4 + cp;
      __hip_atomic_store(hw, pks, __ATOMIC_RELAXED, __HIP_MEMORY_SCOPE_AGENT);

      // drain h-ring stores, then publish this block's flag (plain store, no RMW)
      asm volatile("s_waitcnt vmcnt(0)" ::: "memory");
      if (l == 0) {
        atomicAdd(&lds_arr, 1u);                 // LDS, monotonic
        if (w == 4) {
          long sp = 0;
          while (__hip_atomic_load(&lds_arr, __ATOMIC_RELAXED, __HIP_MEMORY_SCOPE_WORKGROUP)
                 < 4u * (unsigned)(t + 1)) {
            if (++sp > 50000000L) break;
            __builtin_amdgcn_s_sleep(1);
          }
          __hip_atomic_store(myflag, (unsigned)(t + 1), __ATOMIC_RELAXED, __HIP_MEMORY_SCOPE_AGENT);
        }
      }

      // HBM output stores AFTER publication (non-temporal: off L3, write-once)
      if (fout) {
        float hes = sub == 0 ? he[0] : sub == 1 ? he[1] : sub == 2 ? he[2] : he[3];
        float hos = sub == 0 ? ho[0] : sub == 1 ? ho[1] : sub == 2 ? ho[2] : ho[3];
        f32x2 o2; o2.x = hes; o2.y = hos;
        __builtin_nontemporal_store(o2,
            reinterpret_cast<f32x2*>(fout + (size_t)row * (SEQ * HID) + (size_t)t * HID
                                     + nb * 8 + cp * 2));
      }
    }
    __syncthreads();
  }
}

extern "C" void kernel_launch(void* const* d_in, const int* in_sizes, int n_in,
                              void* d_out, int out_size, void* d_ws, size_t ws_size,
                              hipStream_t stream) {
  const float* x   = (const float*)d_in[0];
  const float* Wx0 = (const float*)d_in[1];
  const float* Wh0 = (const float*)d_in[2];
  const float* b0  = (const float*)d_in[3];
  const float* Wx1 = (const float*)d_in[4];
  const float* Wh1 = (const float*)d_in[5];
  const float* b1  = (const float*)d_in[6];
  float* out = (float*)d_out;
  char* ws = (char*)d_ws;

  unsigned short* xb   = (unsigned short*)(ws);                  // 64 MB
  unsigned short* h1   = (unsigned short*)(ws + 67108864);       // 64 MB
  unsigned short* WxT0 = (unsigned short*)(ws + 134217728);      // 8 MB each
  unsigned short* WhT0 = (unsigned short*)(ws + 142606336);
  unsigned short* WxT1 = (unsigned short*)(ws + 150994944);
  unsigned short* WhT1 = (unsigned short*)(ws + 159383552);
  unsigned* bars       = (unsigned*)(ws + 167772160);            // 32 KB flags
  unsigned short* h2   = (unsigned short*)(ws + 167804928);
  int h2mod = (ws_size >= (size_t)167804928 + 67108864) ? 512 : 4;

  (void)hipMemsetAsync(bars, 0, 32768, stream);
  k_castx<<<32768, 256, 0, stream>>>(x, xb);
  k_wtrans<<<4096, 256, 0, stream>>>(Wx0, WxT0);
  k_wtrans<<<4096, 256, 0, stream>>>(Wh0, WhT0);
  k_wtrans<<<4096, 256, 0, stream>>>(Wx1, WxT1);
  k_wtrans<<<4096, 256, 0, stream>>>(Wh1, WhT1);
  k_scan2<<<2 * NBLK, 512, 0, stream>>>(xb, WxT0, WhT0, b0, WxT1, WhT1, b1,
                                        h1, h2, h2mod, out, bars);
}